// Round 7
// baseline (1275.038 us; speedup 1.0000x reference)
//
#include <hip/hip_runtime.h>

#define B_TOTAL 131072
#define PD 200
#define KAPPA 0.8f
#define LAMDA 0.9999f
#define YITA 0.5f
#define MS_KS 216   // M LDS k-stride (27 16B slots, odd -> conflict-free A-frag reads)

typedef short short8 __attribute__((ext_vector_type(8)));
typedef float f32x16 __attribute__((ext_vector_type(16)));
typedef unsigned uint4v __attribute__((ext_vector_type(4)));

static __device__ __forceinline__ float bf2f(unsigned short h) {
  union { unsigned u; float f; } v; v.u = ((unsigned)h) << 16; return v.f;
}
static __device__ __forceinline__ unsigned short f2bf(float f) {
  union { float f; unsigned u; } v; v.f = f;
  unsigned r = v.u + 0x7FFFu + ((v.u >> 16) & 1u);
  return (unsigned short)(r >> 16);
}
static __device__ __forceinline__ float fp_nl(float v) {  // clip(leaky_relu(v),-1,1)
  float t = fmaxf(v, 0.01f * v);
  return fminf(1.f, fmaxf(-1.f, t));
}
static __device__ __forceinline__ unsigned pkbf(float lo, float hi) {
  unsigned r;
  asm("v_cvt_pk_bf16_f32 %0, %1, %2" : "=v"(r) : "v"(lo), "v"(hi));
  return r;
}
// verified R2: swaps 32-lane halves between a,b (a<-{A.lo,B.lo}, b<-{A.hi,B.hi})
static __device__ __forceinline__ void swap32(unsigned &a, unsigned &b) {
  asm("s_nop 1\n\tv_permlane32_swap_b32 %0, %1" : "+v"(a), "+v"(b));
}
static __device__ __forceinline__ uint4v mk4(unsigned a, unsigned b, unsigned c, unsigned d) {
  uint4v v; v[0] = a; v[1] = b; v[2] = c; v[3] = d; return v;
}
static __device__ __forceinline__ short8 u4s8(uint4v w) {
  union { uint4v u; short8 s; } x; x.u = w; return x.s;
}

__global__ void tem_init_m(const float* __restrict__ Min, float* __restrict__ oM) {
  int i = blockIdx.x * 256 + threadIdx.x;
  if (i < PD * PD) oM[i] = LAMDA * Min[i];
}

// ---- macro machinery: all fragment state in NAMED registers, literal indices
#define LDMS(nt, kc) (*(const short8*)(Ms + (((nt) * 32 + cl) * MS_KS + (kc) * 16 + hi * 8)))

// Accumulators FORCED into AGPRs via inline-asm MFMA ("+a"): the 7x16-aligned
// acc tuples + 13x4 pf tuples could not be jointly allocated in the 256
// VGPR-addressable window (R5/R6: per-iteration acc spill = ~700 MB HBM
// writes). AGPR file was empty; unified budget at 1 wave/SIMD is 512.
#define MFMA_A(ACC, KC, NT) do { \
  const short8 _a = LDMS(NT, KC); \
  asm("v_mfma_f32_32x32x16_bf16 %0, %1, %2, %0" : "+a"(ACC) : "v"(_a), "v"(_b)); \
} while (0)

#define STEP(PF, KC) do { \
  const short8 _b = u4s8(PF); \
  MFMA_A(acc0, KC, 0); \
  MFMA_A(acc1, KC, 1); \
  MFMA_A(acc2, KC, 2); \
  MFMA_A(acc3, KC, 3); \
  MFMA_A(acc4, KC, 4); \
  MFMA_A(acc5, KC, 5); \
  MFMA_A(acc6, KC, 6); \
  __builtin_amdgcn_sched_barrier(0); \
} while (0)

#define REPACK_LO(ACC, PF) do { \
  unsigned P0 = pkbf(fp_nl(ACC[0]), fp_nl(ACC[1])); \
  unsigned P1 = pkbf(fp_nl(ACC[2]), fp_nl(ACC[3])); \
  unsigned P2 = pkbf(fp_nl(ACC[4]), fp_nl(ACC[5])); \
  unsigned P3 = pkbf(fp_nl(ACC[6]), fp_nl(ACC[7])); \
  swap32(P0, P2); swap32(P1, P3); \
  PF = mk4(P0, P1, P2, P3); \
} while (0)

#define REPACK_HI(ACC, PF) do { \
  unsigned P4 = pkbf(fp_nl(ACC[8]),  fp_nl(ACC[9])); \
  unsigned P5 = pkbf(fp_nl(ACC[10]), fp_nl(ACC[11])); \
  unsigned P6 = pkbf(fp_nl(ACC[12]), fp_nl(ACC[13])); \
  unsigned P7 = pkbf(fp_nl(ACC[14]), fp_nl(ACC[15])); \
  swap32(P4, P6); swap32(P5, P7); \
  PF = mk4(P4, P5, P6, P7); \
} while (0)

// lane (hi,cl) holds features BB..BB+7 of fragment PF, BB = kc*16 (+8 if hi)
#define FOR_LO(M_) M_(pf0,0) M_(pf1,16) M_(pf2,32) M_(pf3,48) M_(pf4,64) M_(pf5,80) \
                   M_(pf6,96) M_(pf7,112) M_(pf8,128) M_(pf9,144) M_(pf10,160) M_(pf11,176) M_(pf12,192)
#define FOR_HI(M_) M_(pf0,8) M_(pf1,24) M_(pf2,40) M_(pf3,56) M_(pf4,72) M_(pf5,88) \
                   M_(pf6,104) M_(pf7,120) M_(pf8,136) M_(pf9,152) M_(pf10,168) M_(pf11,184)
// hi-branch: pf12 would be features 200..207 (zero pad) -> set to 0 / skipped in epilogues

#define INX(PF, BB) PF = mk4( \
  pkbf(xcv[((BB) + 0) % 10], xcv[((BB) + 1) % 10]), \
  pkbf(xcv[((BB) + 2) % 10], xcv[((BB) + 3) % 10]), \
  pkbf(xcv[((BB) + 4) % 10], xcv[((BB) + 5) % 10]), \
  pkbf(xcv[((BB) + 6) % 10], xcv[((BB) + 7) % 10]));
#define ING(PF, BB) PF = mk4( \
  pkbf(g2v[((BB) + 0) / 10], g2v[((BB) + 1) / 10]), \
  pkbf(g2v[((BB) + 2) / 10], g2v[((BB) + 3) / 10]), \
  pkbf(g2v[((BB) + 4) / 10], g2v[((BB) + 5) / 10]), \
  pkbf(g2v[((BB) + 6) / 10], g2v[((BB) + 7) / 10]));

#define E1W(W, F) { bins[(F) / 10] += bf2f((unsigned short)((W) & 0xFFFFu)); \
                    bins[((F) + 1) / 10] += bf2f((unsigned short)((W) >> 16)); }
#define E1PF(PF, BB) { E1W(PF[0], (BB) + 0) E1W(PF[1], (BB) + 2) E1W(PF[2], (BB) + 4) E1W(PF[3], (BB) + 6) }

#define E2AW(W, F) { ta[(F) % 10] += bf2f((unsigned short)((W) & 0xFFFFu)); \
                     ta[((F) + 1) % 10] += bf2f((unsigned short)((W) >> 16)); }
#define E2APF(PF, BB) { E2AW(PF[0], (BB) + 0) E2AW(PF[1], (BB) + 2) E2AW(PF[2], (BB) + 4) E2AW(PF[3], (BB) + 6) }

#define E2BW(W, F) { \
  const float p0_ = bf2f((unsigned short)((W) & 0xFFFFu)); \
  const float p1_ = bf2f((unsigned short)((W) >> 16)); \
  const float q0_ = fp_nl(g2v[(F) / 10] * xcv[(F) % 10]); \
  const float q1_ = fp_nl(g2v[((F) + 1) / 10] * xcv[((F) + 1) % 10]); \
  dWp[(size_t)(F) * B_TOTAL + r] = f2bf(q0_ - p0_); \
  sWp[(size_t)(F) * B_TOTAL + r] = f2bf(q0_ + p0_); \
  dWp[(size_t)((F) + 1) * B_TOTAL + r] = f2bf(q1_ - p1_); \
  sWp[(size_t)((F) + 1) * B_TOTAL + r] = f2bf(q1_ + p1_); \
}
#define E2BPF(PF, BB) { E2BW(PF[0], (BB) + 0) E2BW(PF[1], (BB) + 2) E2BW(PF[2], (BB) + 4) E2BW(PF[3], (BB) + 6) }

// 256 threads (4 waves): 1 wave/SIMD -> full unified reg budget (R1: 208 VGPR,
// no scratch). 512-thr blocks pinned the compiler to 128 VGPR (R2-R4 spill).
__global__ __launch_bounds__(256, 1) void tem_main(
    const float* __restrict__ xin, const float* __restrict__ gin,
    const float* __restrict__ Min, const float* __restrict__ Wc,
    const float* __restrict__ W1ie, const float* __restrict__ b1ie,
    const float* __restrict__ W2ie, const float* __restrict__ b2ie,
    const float* __restrict__ W1gg, const float* __restrict__ b1gg,
    const float* __restrict__ W2gg, const float* __restrict__ b2gg,
    const float* __restrict__ Wsp, const float* __restrict__ bsp,
    float* __restrict__ o_ginf, float* __restrict__ o_xinf,
    float* __restrict__ o_g, float* __restrict__ o_x,
    unsigned short* __restrict__ dWp, unsigned short* __restrict__ sWp) {
  // LDS: 96768 + 2560 + 10240 = 109568 B
  __shared__ __attribute__((aligned(16))) unsigned short Ms[224 * MS_KS];
  __shared__ unsigned short xcS[128 * 10];
  __shared__ float g2S[128 * 20];

  const int tid = threadIdx.x;
  const int lane = tid & 63;
  const int wid = tid >> 6;      // 0..3
  const int cl = lane & 31;
  const int hi = lane >> 5;
  const int r0 = blockIdx.x * 128;

  {
    unsigned* Ms32 = (unsigned*)Ms;
    for (int i = tid; i < 224 * MS_KS / 2; i += 256) Ms32[i] = 0u;
  }
  __syncthreads();
  for (int i = tid; i < 200 * 224; i += 256) {
    const int k = i / 224, n = i - k * 224;
    if (n < 200) {
      float v = Min[k * 200 + n];
      if (k == n) v += KAPPA;
      Ms[n * MS_KS + k] = f2bf(v);
    }
  }

  // prologue: threads 0..127 -> g2 MLP; 128..255 -> xc
  if (tid < 128) {
    const int r = r0 + tid;
    float gv[20];
#pragma unroll
    for (int i = 0; i < 20; ++i) gv[i] = gin[(size_t)r * 20 + i];
    float h[40];
#pragma unroll
    for (int u = 0; u < 40; ++u) h[u] = b1gg[u];
#pragma unroll
    for (int i = 0; i < 20; ++i)
#pragma unroll
      for (int u = 0; u < 40; ++u) h[u] += gv[i] * W1gg[i * 40 + u];
#pragma unroll
    for (int u = 0; u < 40; ++u) h[u] = (h[u] > 0.f) ? h[u] : (expf(h[u]) - 1.f);
#pragma unroll
    for (int o = 0; o < 20; ++o) {
      float v = b2gg[o];
#pragma unroll
      for (int u = 0; u < 40; ++u) v += h[u] * W2gg[u * 20 + o];
      g2S[tid * 20 + o] = tanhf(v);
    }
  } else {
    const int rr2 = tid - 128;
    const int r = r0 + rr2;
    float xc[10];
#pragma unroll
    for (int o = 0; o < 10; ++o) xc[o] = 0.f;
    for (int j = 0; j < 45; ++j) {
      const float xv = xin[(size_t)r * 45 + j];
#pragma unroll
      for (int o = 0; o < 10; ++o) xc[o] += xv * Wc[j * 10 + o];
    }
#pragma unroll
    for (int o = 0; o < 10; ++o) xcS[rr2 * 10 + o] = f2bf(xc[o]);
  }
  __syncthreads();

  // P1: write g_ and x_ outputs
  for (int i = tid; i < 128 * 200; i += 256) {
    const int rP = i / 200, j = i - rP * 200;
    o_g[(size_t)(r0 + rP) * 200 + j] = g2S[rP * 20 + j / 10];
    o_x[(size_t)(r0 + rP) * 200 + j] = bf2f(xcS[rP * 10 + (j % 10)]);
  }

  const int rr = wid * 32 + cl;   // block-row this lane owns (0..127)
  const int r = r0 + rr;          // global row

  uint4v pf0, pf1, pf2, pf3, pf4, pf5, pf6, pf7, pf8, pf9, pf10, pf11, pf12;

#pragma unroll 1
  for (int ret = 0; ret < 2; ++ret) {
    // ---- build initial fragments (named regs, literal indices)
    if (ret == 0) {
      float xcv[10];
#pragma unroll
      for (int o = 0; o < 10; ++o) xcv[o] = bf2f(xcS[rr * 10 + o]);
      if (hi == 0) { FOR_LO(INX) }
      else         { FOR_HI(INX) pf12 = mk4(0u, 0u, 0u, 0u); }
    } else {
      float g2v[20];
#pragma unroll
      for (int o = 0; o < 20; ++o) g2v[o] = g2S[rr * 20 + o];
      if (hi == 0) { FOR_LO(ING) }
      else         { FOR_HI(ING) pf12 = mk4(0u, 0u, 0u, 0u); }
    }

    // ---- 5 attractor iterations, register-resident (acc in AGPR, pf in VGPR)
#pragma unroll 1
    for (int it = 0; it < 5; ++it) {
      f32x16 acc0 = {}, acc1 = {}, acc2 = {}, acc3 = {}, acc4 = {}, acc5 = {}, acc6 = {};
      STEP(pf0, 0);  STEP(pf1, 1);  STEP(pf2, 2);  STEP(pf3, 3);
      STEP(pf4, 4);  STEP(pf5, 5);  STEP(pf6, 6);  STEP(pf7, 7);
      STEP(pf8, 8);  STEP(pf9, 9);  STEP(pf10, 10); STEP(pf11, 11);
      STEP(pf12, 12);
      REPACK_LO(acc0, pf0);  REPACK_HI(acc0, pf1);
      REPACK_LO(acc1, pf2);  REPACK_HI(acc1, pf3);
      REPACK_LO(acc2, pf4);  REPACK_HI(acc2, pf5);
      REPACK_LO(acc3, pf6);  REPACK_HI(acc3, pf7);
      REPACK_LO(acc4, pf8);  REPACK_HI(acc4, pf9);
      REPACK_LO(acc5, pf10); REPACK_HI(acc5, pf11);
      REPACK_LO(acc6, pf12);              // hi half of tile 6 (n=208..223) dropped
    }

    if (ret == 0) {
      // ---- E1: g_inf = clip(MLP(px @ W_repeat^T))
      float bins[20];
#pragma unroll
      for (int t = 0; t < 20; ++t) bins[t] = 0.f;
      if (hi == 0) { FOR_LO(E1PF) } else { FOR_HI(E1PF) }
#pragma unroll
      for (int t = 0; t < 20; ++t) bins[t] += __shfl_xor(bins[t], 32);
      float h[40];
#pragma unroll
      for (int u = 0; u < 40; ++u) h[u] = b1ie[u];
#pragma unroll
      for (int gg = 0; gg < 20; ++gg) {
        const float bv = bins[gg];
#pragma unroll
        for (int u = 0; u < 40; ++u) h[u] += bv * W1ie[gg * 40 + u];
      }
#pragma unroll
      for (int u = 0; u < 40; ++u) h[u] = (h[u] > 0.f) ? h[u] : (expf(h[u]) - 1.f);
#pragma unroll
      for (int oi = 0; oi < 10; ++oi) {
        const int o = hi * 10 + oi;
        float v = b2ie[o];
#pragma unroll
        for (int u = 0; u < 40; ++u) v += h[u] * W2ie[u * 20 + o];
        o_ginf[(size_t)r * 20 + o] = fminf(1.f, fmaxf(-1.f, v));
      }
    } else {
      // ---- E2a: x_inf = (p @ W_tile^T) @ W_sp + b_sp
      float ta[10];
#pragma unroll
      for (int t = 0; t < 10; ++t) ta[t] = 0.f;
      if (hi == 0) { FOR_LO(E2APF) } else { FOR_HI(E2APF) }
#pragma unroll
      for (int t = 0; t < 10; ++t) ta[t] += __shfl_xor(ta[t], 32);
      {
        const int o0 = hi ? 23 : 0, o1 = hi ? 45 : 23;
        for (int o = o0; o < o1; ++o) {
          float v = bsp[o];
#pragma unroll
          for (int a = 0; a < 10; ++a) v += ta[a] * Wsp[a * 45 + o];
          o_xinf[(size_t)r * 45 + o] = v;
        }
      }
      // ---- E2b: d/s staging, feature-major [f*B + r]
      {
        float xcv[10], g2v[20];
#pragma unroll
        for (int o = 0; o < 10; ++o) xcv[o] = bf2f(xcS[rr * 10 + o]);
#pragma unroll
        for (int o = 0; o < 20; ++o) g2v[o] = g2S[rr * 20 + o];
        if (hi == 0) { FOR_LO(E2BPF) } else { FOR_HI(E2BPF) }
      }
    }
  }
}

__global__ __launch_bounds__(448, 1) void tem_hebb(
    const unsigned short* __restrict__ dWp, const unsigned short* __restrict__ sWp,
    float* __restrict__ oM) {
  const int tid = threadIdx.x;
  const int lane = tid & 63, wid = tid >> 6;   // 7 waves
  const int cl = lane & 31, hi = lane >> 5;
  f32x16 hacc[7];
#pragma unroll
  for (int nt = 0; nt < 7; ++nt)
#pragma unroll
    for (int q = 0; q < 16; ++q) hacc[nt][q] = 0.f;

  const int fa = wid * 32 + cl;
  const size_t arow = (size_t)fa * B_TOTAL;
  const int kb0 = blockIdx.x * 512;
  const short8 zf = {0, 0, 0, 0, 0, 0, 0, 0};

  for (int kch = 0; kch < 32; ++kch) {
    const int kb = kb0 + kch * 16 + hi * 8;
    short8 a = zf;
    if (fa < 200) a = *(const short8*)(dWp + arow + kb);
#pragma unroll
    for (int nt = 0; nt < 7; ++nt) {
      const int fb = nt * 32 + cl;
      short8 b = zf;
      if (fb < 200) b = *(const short8*)(sWp + (size_t)fb * B_TOTAL + kb);
      hacc[nt] = __builtin_amdgcn_mfma_f32_32x32x16_bf16(a, b, hacc[nt], 0, 0, 0);
    }
  }
  const float scale = YITA / (float)B_TOTAL;
#pragma unroll
  for (int nt = 0; nt < 7; ++nt) {
    const int j = nt * 32 + cl;
    if (j < 200) {
#pragma unroll
      for (int rg = 0; rg < 16; ++rg) {
        const int ii = wid * 32 + (rg & 3) + 8 * (rg >> 2) + 4 * hi;
        if (ii < 200) atomicAdd(&oM[ii * 200 + j], hacc[nt][rg] * scale);
      }
    }
  }
}

extern "C" void kernel_launch(void* const* d_in, const int* in_sizes, int n_in,
                              void* d_out, int out_size, void* d_ws, size_t ws_size,
                              hipStream_t stream) {
  (void)in_sizes; (void)n_in; (void)out_size; (void)ws_size;
  const float* xin  = (const float*)d_in[0];
  const float* gin  = (const float*)d_in[1];
  const float* Min  = (const float*)d_in[2];
  const float* Wc   = (const float*)d_in[3];
  const float* W1ie = (const float*)d_in[4];
  const float* b1ie = (const float*)d_in[5];
  const float* W2ie = (const float*)d_in[6];
  const float* b2ie = (const float*)d_in[7];
  const float* W1gg = (const float*)d_in[8];
  const float* b1gg = (const float*)d_in[9];
  const float* W2gg = (const float*)d_in[10];
  const float* b2gg = (const float*)d_in[11];
  const float* Wsp  = (const float*)d_in[12];
  const float* bsp  = (const float*)d_in[13];

  float* out = (float*)d_out;
  float* o_ginf = out;
  float* o_xinf = out + (size_t)B_TOTAL * 20;
  float* o_g    = out + (size_t)B_TOTAL * 65;
  float* o_x    = out + (size_t)B_TOTAL * 265;
  float* o_M    = out + (size_t)B_TOTAL * 465;

  unsigned short* dWp = (unsigned short*)d_ws;
  unsigned short* sWp = dWp + (size_t)PD * B_TOTAL;

  tem_init_m<<<(PD * PD + 255) / 256, 256, 0, stream>>>(Min, o_M);
  tem_main<<<1024, 256, 0, stream>>>(xin, gin, Min, Wc, W1ie, b1ie, W2ie, b2ie,
                                     W1gg, b1gg, W2gg, b2gg, Wsp, bsp,
                                     o_ginf, o_xinf, o_g, o_x, dWp, sWp);
  tem_hebb<<<256, 448, 0, stream>>>(dWp, sWp, o_M);
}

// Round 8
// 1062.150 us; speedup vs baseline: 1.2004x; 1.2004x over previous
//
#include <hip/hip_runtime.h>

#define B_TOTAL 131072
#define PD 200
#define KAPPA 0.8f
#define LAMDA 0.9999f
#define YITA 0.5f
#define MS_KS 216   // M LDS k-stride (27 16B slots, odd -> minimal-conflict A reads)

typedef short short8 __attribute__((ext_vector_type(8)));
typedef float f32x16 __attribute__((ext_vector_type(16)));
typedef unsigned uint4v __attribute__((ext_vector_type(4)));

static __device__ __forceinline__ float bf2f(unsigned short h) {
  union { unsigned u; float f; } v; v.u = ((unsigned)h) << 16; return v.f;
}
static __device__ __forceinline__ unsigned short f2bf(float f) {
  union { float f; unsigned u; } v; v.f = f;
  unsigned r = v.u + 0x7FFFu + ((v.u >> 16) & 1u);
  return (unsigned short)(r >> 16);
}
static __device__ __forceinline__ float fp_nl(float v) {  // clip(leaky_relu(v),-1,1)
  float t = fmaxf(v, 0.01f * v);
  return fminf(1.f, fmaxf(-1.f, t));
}
static __device__ __forceinline__ unsigned pkbf(float lo, float hi) {
  unsigned r;
  asm("v_cvt_pk_bf16_f32 %0, %1, %2" : "=v"(r) : "v"(lo), "v"(hi));
  return r;
}
// verified R2-R7: swaps 32-lane halves between a,b
static __device__ __forceinline__ void swap32(unsigned &a, unsigned &b) {
  asm("s_nop 1\n\tv_permlane32_swap_b32 %0, %1" : "+v"(a), "+v"(b));
}
static __device__ __forceinline__ uint4v mk4(unsigned a, unsigned b, unsigned c, unsigned d) {
  uint4v v; v[0] = a; v[1] = b; v[2] = c; v[3] = d; return v;
}
static __device__ __forceinline__ short8 u4s8(uint4v w) {
  union { uint4v u; short8 s; } x; x.u = w; return x.s;
}

__global__ void tem_init_m(const float* __restrict__ Min, float* __restrict__ oM) {
  int i = blockIdx.x * 256 + threadIdx.x;
  if (i < PD * PD) oM[i] = LAMDA * Min[i];
}

// ---- fragment state lives in WAVE-PRIVATE LDS (Pb), not registers.
// R2-R7 post-mortems: register-resident pf (52 regs) + acc (112) could never
// be kept resident by the backend (persistent ~700 MB scratch traffic,
// unchanged by launch_bounds / named regs / sched_barrier / AGPR-forcing).
// LDS round-trip of the PACKED B-fragments costs 26 b128 LDS ops/iter/wave
// (vs R1's 112 scalar b16 scatter + 5.2M bank conflicts) and bounds live
// registers to acc+temps (~160) - the regime R1 proved spill-free.
#define LDMS(nt, kc) (*(const short8*)(Ms + (((nt) * 32 + cl) * MS_KS + (kc) * 16 + hi * 8)))
#define PFLD(KC) (((const uint4v*)Pb)[(pbW + (KC)) * 64 + lane])
#define PFST(KC, V) (((uint4v*)Pb)[(pbW + (KC)) * 64 + lane] = (V))

#define STEP(KC) do { \
  const short8 _b = u4s8(PFLD(KC)); \
  acc0 = __builtin_amdgcn_mfma_f32_32x32x16_bf16(LDMS(0, KC), _b, acc0, 0, 0, 0); \
  acc1 = __builtin_amdgcn_mfma_f32_32x32x16_bf16(LDMS(1, KC), _b, acc1, 0, 0, 0); \
  acc2 = __builtin_amdgcn_mfma_f32_32x32x16_bf16(LDMS(2, KC), _b, acc2, 0, 0, 0); \
  acc3 = __builtin_amdgcn_mfma_f32_32x32x16_bf16(LDMS(3, KC), _b, acc3, 0, 0, 0); \
  acc4 = __builtin_amdgcn_mfma_f32_32x32x16_bf16(LDMS(4, KC), _b, acc4, 0, 0, 0); \
  acc5 = __builtin_amdgcn_mfma_f32_32x32x16_bf16(LDMS(5, KC), _b, acc5, 0, 0, 0); \
  acc6 = __builtin_amdgcn_mfma_f32_32x32x16_bf16(LDMS(6, KC), _b, acc6, 0, 0, 0); \
  __builtin_amdgcn_sched_barrier(0); \
} while (0)

#define REPACK_LO(ACC, KC) do { \
  unsigned P0 = pkbf(fp_nl(ACC[0]), fp_nl(ACC[1])); \
  unsigned P1 = pkbf(fp_nl(ACC[2]), fp_nl(ACC[3])); \
  unsigned P2 = pkbf(fp_nl(ACC[4]), fp_nl(ACC[5])); \
  unsigned P3 = pkbf(fp_nl(ACC[6]), fp_nl(ACC[7])); \
  swap32(P0, P2); swap32(P1, P3); \
  PFST(KC, mk4(P0, P1, P2, P3)); \
} while (0)

#define REPACK_HI(ACC, KC) do { \
  unsigned P4 = pkbf(fp_nl(ACC[8]),  fp_nl(ACC[9])); \
  unsigned P5 = pkbf(fp_nl(ACC[10]), fp_nl(ACC[11])); \
  unsigned P6 = pkbf(fp_nl(ACC[12]), fp_nl(ACC[13])); \
  unsigned P7 = pkbf(fp_nl(ACC[14]), fp_nl(ACC[15])); \
  swap32(P4, P6); swap32(P5, P7); \
  PFST(KC, mk4(P4, P5, P6, P7)); \
} while (0)

// lane (hi,cl) holds features BB..BB+7 of LDS fragment KC, BB = kc*16 (+8 if hi)
#define FOR_LO(M_) M_(0,0) M_(1,16) M_(2,32) M_(3,48) M_(4,64) M_(5,80) \
                   M_(6,96) M_(7,112) M_(8,128) M_(9,144) M_(10,160) M_(11,176) M_(12,192)
#define FOR_HI(M_) M_(0,8) M_(1,24) M_(2,40) M_(3,56) M_(4,72) M_(5,88) \
                   M_(6,104) M_(7,120) M_(8,136) M_(9,152) M_(10,168) M_(11,184)

#define INX(KC, BB) PFST(KC, mk4( \
  pkbf(xcv[((BB) + 0) % 10], xcv[((BB) + 1) % 10]), \
  pkbf(xcv[((BB) + 2) % 10], xcv[((BB) + 3) % 10]), \
  pkbf(xcv[((BB) + 4) % 10], xcv[((BB) + 5) % 10]), \
  pkbf(xcv[((BB) + 6) % 10], xcv[((BB) + 7) % 10])));
#define ING(KC, BB) PFST(KC, mk4( \
  pkbf(g2v[((BB) + 0) / 10], g2v[((BB) + 1) / 10]), \
  pkbf(g2v[((BB) + 2) / 10], g2v[((BB) + 3) / 10]), \
  pkbf(g2v[((BB) + 4) / 10], g2v[((BB) + 5) / 10]), \
  pkbf(g2v[((BB) + 6) / 10], g2v[((BB) + 7) / 10])));

#define E1W(W, F) { bins[(F) / 10] += bf2f((unsigned short)((W) & 0xFFFFu)); \
                    bins[((F) + 1) / 10] += bf2f((unsigned short)((W) >> 16)); }
#define E1PF(KC, BB) { const uint4v W_ = PFLD(KC); \
  E1W(W_[0], (BB) + 0) E1W(W_[1], (BB) + 2) E1W(W_[2], (BB) + 4) E1W(W_[3], (BB) + 6) }

#define E2AW(W, F) { ta[(F) % 10] += bf2f((unsigned short)((W) & 0xFFFFu)); \
                     ta[((F) + 1) % 10] += bf2f((unsigned short)((W) >> 16)); }
#define E2APF(KC, BB) { const uint4v W_ = PFLD(KC); \
  E2AW(W_[0], (BB) + 0) E2AW(W_[1], (BB) + 2) E2AW(W_[2], (BB) + 4) E2AW(W_[3], (BB) + 6) }

#define E2BW(W, F) { \
  const float p0_ = bf2f((unsigned short)((W) & 0xFFFFu)); \
  const float p1_ = bf2f((unsigned short)((W) >> 16)); \
  const float q0_ = fp_nl(g2v[(F) / 10] * xcv[(F) % 10]); \
  const float q1_ = fp_nl(g2v[((F) + 1) / 10] * xcv[((F) + 1) % 10]); \
  dWp[(size_t)(F) * B_TOTAL + r] = f2bf(q0_ - p0_); \
  sWp[(size_t)(F) * B_TOTAL + r] = f2bf(q0_ + p0_); \
  dWp[(size_t)((F) + 1) * B_TOTAL + r] = f2bf(q1_ - p1_); \
  sWp[(size_t)((F) + 1) * B_TOTAL + r] = f2bf(q1_ + p1_); \
}
#define E2BPF(KC, BB) { const uint4v W_ = PFLD(KC); \
  E2BW(W_[0], (BB) + 0) E2BW(W_[1], (BB) + 2) E2BW(W_[2], (BB) + 4) E2BW(W_[3], (BB) + 6) }

// 256 threads (4 waves, 1/SIMD): the only config that never spilled (R1).
__global__ __launch_bounds__(256, 1) void tem_main(
    const float* __restrict__ xin, const float* __restrict__ gin,
    const float* __restrict__ Min, const float* __restrict__ Wc,
    const float* __restrict__ W1ie, const float* __restrict__ b1ie,
    const float* __restrict__ W2ie, const float* __restrict__ b2ie,
    const float* __restrict__ W1gg, const float* __restrict__ b1gg,
    const float* __restrict__ W2gg, const float* __restrict__ b2gg,
    const float* __restrict__ Wsp, const float* __restrict__ bsp,
    float* __restrict__ o_ginf, float* __restrict__ o_xinf,
    float* __restrict__ o_g, float* __restrict__ o_x,
    unsigned short* __restrict__ dWp, unsigned short* __restrict__ sWp) {
  // LDS: 96768 + 53248 + 2560 + 10240 = 162816 B
  __shared__ __attribute__((aligned(16))) unsigned short Ms[224 * MS_KS];
  __shared__ __attribute__((aligned(16))) unsigned Pb[4 * 13 * 64 * 4];
  __shared__ unsigned short xcS[128 * 10];
  __shared__ float g2S[128 * 20];

  const int tid = threadIdx.x;
  const int lane = tid & 63;
  const int wid = tid >> 6;      // 0..3
  const int cl = lane & 31;
  const int hi = lane >> 5;
  const int pbW = wid * 13;      // per-wave Pb fragment base

  // ---- stage M^T (+kappa*I) once per block
  {
    unsigned* Ms32 = (unsigned*)Ms;
    for (int i = tid; i < 224 * MS_KS / 2; i += 256) Ms32[i] = 0u;
  }
  __syncthreads();
  for (int i = tid; i < 200 * 224; i += 256) {
    const int k = i / 224, n = i - k * 224;
    if (n < 200) {
      float v = Min[k * 200 + n];
      if (k == n) v += KAPPA;
      Ms[n * MS_KS + k] = f2bf(v);
    }
  }

#pragma unroll 1
  for (int chunk = 0; chunk < 4; ++chunk) {
    const int r0 = (blockIdx.x * 4 + chunk) * 128;

    __syncthreads();   // Ms ready (chunk 0) / all waves done with xcS,g2S (chunks 1+)

    // prologue: threads 0..127 -> g2 MLP; 128..255 -> xc
    if (tid < 128) {
      const int rq = r0 + tid;
      float gv[20];
#pragma unroll
      for (int i = 0; i < 20; ++i) gv[i] = gin[(size_t)rq * 20 + i];
      float h[40];
#pragma unroll
      for (int u = 0; u < 40; ++u) h[u] = b1gg[u];
#pragma unroll
      for (int i = 0; i < 20; ++i)
#pragma unroll
        for (int u = 0; u < 40; ++u) h[u] += gv[i] * W1gg[i * 40 + u];
#pragma unroll
      for (int u = 0; u < 40; ++u) h[u] = (h[u] > 0.f) ? h[u] : (expf(h[u]) - 1.f);
#pragma unroll
      for (int o = 0; o < 20; ++o) {
        float v = b2gg[o];
#pragma unroll
        for (int u = 0; u < 40; ++u) v += h[u] * W2gg[u * 20 + o];
        g2S[tid * 20 + o] = tanhf(v);
      }
    } else {
      const int rr2 = tid - 128;
      const int rq = r0 + rr2;
      float xc[10];
#pragma unroll
      for (int o = 0; o < 10; ++o) xc[o] = 0.f;
      for (int j = 0; j < 45; ++j) {
        const float xv = xin[(size_t)rq * 45 + j];
#pragma unroll
        for (int o = 0; o < 10; ++o) xc[o] += xv * Wc[j * 10 + o];
      }
#pragma unroll
      for (int o = 0; o < 10; ++o) xcS[rr2 * 10 + o] = f2bf(xc[o]);
    }
    __syncthreads();

    // P1: write g_ and x_ outputs
    for (int i = tid; i < 128 * 200; i += 256) {
      const int rP = i / 200, j = i - rP * 200;
      o_g[(size_t)(r0 + rP) * 200 + j] = g2S[rP * 20 + j / 10];
      o_x[(size_t)(r0 + rP) * 200 + j] = bf2f(xcS[rP * 10 + (j % 10)]);
    }

    const int rr = wid * 32 + cl;   // block-row this lane owns (0..127)
    const int r = r0 + rr;          // global row

    // NO barriers below: each wave touches only its own Pb slice; Ms read-only.
#pragma unroll 1
    for (int ret = 0; ret < 2; ++ret) {
      if (ret == 0) {
        float xcv[10];
#pragma unroll
        for (int o = 0; o < 10; ++o) xcv[o] = bf2f(xcS[rr * 10 + o]);
        if (hi == 0) { FOR_LO(INX) }
        else         { FOR_HI(INX) PFST(12, mk4(0u, 0u, 0u, 0u)); }
      } else {
        float g2v[20];
#pragma unroll
        for (int o = 0; o < 20; ++o) g2v[o] = g2S[rr * 20 + o];
        if (hi == 0) { FOR_LO(ING) }
        else         { FOR_HI(ING) PFST(12, mk4(0u, 0u, 0u, 0u)); }
      }

#pragma unroll 1
      for (int it = 0; it < 5; ++it) {
        f32x16 acc0 = {}, acc1 = {}, acc2 = {}, acc3 = {}, acc4 = {}, acc5 = {}, acc6 = {};
        STEP(0);  STEP(1);  STEP(2);  STEP(3);  STEP(4);  STEP(5);  STEP(6);
        STEP(7);  STEP(8);  STEP(9);  STEP(10); STEP(11); STEP(12);
        REPACK_LO(acc0, 0);  REPACK_HI(acc0, 1);
        REPACK_LO(acc1, 2);  REPACK_HI(acc1, 3);
        REPACK_LO(acc2, 4);  REPACK_HI(acc2, 5);
        REPACK_LO(acc3, 6);  REPACK_HI(acc3, 7);
        REPACK_LO(acc4, 8);  REPACK_HI(acc4, 9);
        REPACK_LO(acc5, 10); REPACK_HI(acc5, 11);
        REPACK_LO(acc6, 12);              // hi half of tile 6 (n=208..223) dropped
      }

      if (ret == 0) {
        // E1: g_inf = clip(MLP(px @ W_repeat^T))
        float bins[20];
#pragma unroll
        for (int t = 0; t < 20; ++t) bins[t] = 0.f;
        if (hi == 0) { FOR_LO(E1PF) } else { FOR_HI(E1PF) }
#pragma unroll
        for (int t = 0; t < 20; ++t) bins[t] += __shfl_xor(bins[t], 32);
        float h[40];
#pragma unroll
        for (int u = 0; u < 40; ++u) h[u] = b1ie[u];
#pragma unroll
        for (int gg = 0; gg < 20; ++gg) {
          const float bv = bins[gg];
#pragma unroll
          for (int u = 0; u < 40; ++u) h[u] += bv * W1ie[gg * 40 + u];
        }
#pragma unroll
        for (int u = 0; u < 40; ++u) h[u] = (h[u] > 0.f) ? h[u] : (expf(h[u]) - 1.f);
#pragma unroll
        for (int oi = 0; oi < 10; ++oi) {
          const int o = hi * 10 + oi;
          float v = b2ie[o];
#pragma unroll
          for (int u = 0; u < 40; ++u) v += h[u] * W2ie[u * 20 + o];
          o_ginf[(size_t)r * 20 + o] = fminf(1.f, fmaxf(-1.f, v));
        }
      } else {
        // E2a: x_inf = (p @ W_tile^T) @ W_sp + b_sp
        float ta[10];
#pragma unroll
        for (int t = 0; t < 10; ++t) ta[t] = 0.f;
        if (hi == 0) { FOR_LO(E2APF) } else { FOR_HI(E2APF) }
#pragma unroll
        for (int t = 0; t < 10; ++t) ta[t] += __shfl_xor(ta[t], 32);
        {
          const int o0 = hi ? 23 : 0, o1 = hi ? 45 : 23;
          for (int o = o0; o < o1; ++o) {
            float v = bsp[o];
#pragma unroll
            for (int a = 0; a < 10; ++a) v += ta[a] * Wsp[a * 45 + o];
            o_xinf[(size_t)r * 45 + o] = v;
          }
        }
        // E2b: d/s staging, feature-major [f*B + r]
        {
          float xcv[10], g2v[20];
#pragma unroll
          for (int o = 0; o < 10; ++o) xcv[o] = bf2f(xcS[rr * 10 + o]);
#pragma unroll
          for (int o = 0; o < 20; ++o) g2v[o] = g2S[rr * 20 + o];
          if (hi == 0) { FOR_LO(E2BPF) } else { FOR_HI(E2BPF) }
        }
      }
    }
  }
}

__global__ __launch_bounds__(448, 1) void tem_hebb(
    const unsigned short* __restrict__ dWp, const unsigned short* __restrict__ sWp,
    float* __restrict__ oM) {
  const int tid = threadIdx.x;
  const int lane = tid & 63, wid = tid >> 6;   // 7 waves
  const int cl = lane & 31, hi = lane >> 5;
  f32x16 hacc[7];
#pragma unroll
  for (int nt = 0; nt < 7; ++nt)
#pragma unroll
    for (int q = 0; q < 16; ++q) hacc[nt][q] = 0.f;

  const int fa = wid * 32 + cl;
  const size_t arow = (size_t)fa * B_TOTAL;
  const int kb0 = blockIdx.x * 512;
  const short8 zf = {0, 0, 0, 0, 0, 0, 0, 0};

  for (int kch = 0; kch < 32; ++kch) {
    const int kb = kb0 + kch * 16 + hi * 8;
    short8 a = zf;
    if (fa < 200) a = *(const short8*)(dWp + arow + kb);
#pragma unroll
    for (int nt = 0; nt < 7; ++nt) {
      const int fb = nt * 32 + cl;
      short8 b = zf;
      if (fb < 200) b = *(const short8*)(sWp + (size_t)fb * B_TOTAL + kb);
      hacc[nt] = __builtin_amdgcn_mfma_f32_32x32x16_bf16(a, b, hacc[nt], 0, 0, 0);
    }
  }
  const float scale = YITA / (float)B_TOTAL;
#pragma unroll
  for (int nt = 0; nt < 7; ++nt) {
    const int j = nt * 32 + cl;
    if (j < 200) {
#pragma unroll
      for (int rg = 0; rg < 16; ++rg) {
        const int ii = wid * 32 + (rg & 3) + 8 * (rg >> 2) + 4 * hi;
        if (ii < 200) atomicAdd(&oM[ii * 200 + j], hacc[nt][rg] * scale);
      }
    }
  }
}

extern "C" void kernel_launch(void* const* d_in, const int* in_sizes, int n_in,
                              void* d_out, int out_size, void* d_ws, size_t ws_size,
                              hipStream_t stream) {
  (void)in_sizes; (void)n_in; (void)out_size; (void)ws_size;
  const float* xin  = (const float*)d_in[0];
  const float* gin  = (const float*)d_in[1];
  const float* Min  = (const float*)d_in[2];
  const float* Wc   = (const float*)d_in[3];
  const float* W1ie = (const float*)d_in[4];
  const float* b1ie = (const float*)d_in[5];
  const float* W2ie = (const float*)d_in[6];
  const float* b2ie = (const float*)d_in[7];
  const float* W1gg = (const float*)d_in[8];
  const float* b1gg = (const float*)d_in[9];
  const float* W2gg = (const float*)d_in[10];
  const float* b2gg = (const float*)d_in[11];
  const float* Wsp  = (const float*)d_in[12];
  const float* bsp  = (const float*)d_in[13];

  float* out = (float*)d_out;
  float* o_ginf = out;
  float* o_xinf = out + (size_t)B_TOTAL * 20;
  float* o_g    = out + (size_t)B_TOTAL * 65;
  float* o_x    = out + (size_t)B_TOTAL * 265;
  float* o_M    = out + (size_t)B_TOTAL * 465;

  unsigned short* dWp = (unsigned short*)d_ws;
  unsigned short* sWp = dWp + (size_t)PD * B_TOTAL;

  tem_init_m<<<(PD * PD + 255) / 256, 256, 0, stream>>>(Min, o_M);
  tem_main<<<256, 256, 0, stream>>>(xin, gin, Min, Wc, W1ie, b1ie, W2ie, b2ie,
                                    W1gg, b1gg, W2gg, b2gg, Wsp, bsp,
                                    o_ginf, o_xinf, o_g, o_x, dWp, sWp);
  tem_hebb<<<256, 448, 0, stream>>>(dWp, sWp, o_M);
}

// Round 9
// 585.351 us; speedup vs baseline: 2.1782x; 1.8146x over previous
//
#include <hip/hip_runtime.h>

#define B_TOTAL 131072
#define PD 200
#define KAPPA 0.8f
#define LAMDA 0.9999f
#define YITA 0.5f
#define MS_KS 216   // M LDS k-stride (27 16B slots, odd -> minimal-conflict A reads)
#define HB_RS 72    // hebb LDS row-stride (9 slots, odd)

typedef short short8 __attribute__((ext_vector_type(8)));
typedef short short4v __attribute__((ext_vector_type(4)));
typedef float f32x16 __attribute__((ext_vector_type(16)));
typedef unsigned uint4v __attribute__((ext_vector_type(4)));

static __device__ __forceinline__ float bf2f(unsigned short h) {
  union { unsigned u; float f; } v; v.u = ((unsigned)h) << 16; return v.f;
}
static __device__ __forceinline__ unsigned short f2bf(float f) {
  union { float f; unsigned u; } v; v.f = f;
  unsigned r = v.u + 0x7FFFu + ((v.u >> 16) & 1u);
  return (unsigned short)(r >> 16);
}
static __device__ __forceinline__ float fp_nl(float v) {  // clip(leaky_relu(v),-1,1)
  float t = fmaxf(v, 0.01f * v);
  return fminf(1.f, fmaxf(-1.f, t));
}
static __device__ __forceinline__ unsigned pkbf(float lo, float hi) {
  unsigned r;
  asm("v_cvt_pk_bf16_f32 %0, %1, %2" : "=v"(r) : "v"(lo), "v"(hi));
  return r;
}
// verified R2-R8: swaps 32-lane halves between a,b
static __device__ __forceinline__ void swap32(unsigned &a, unsigned &b) {
  asm("s_nop 1\n\tv_permlane32_swap_b32 %0, %1" : "+v"(a), "+v"(b));
}
static __device__ __forceinline__ uint4v mk4(unsigned a, unsigned b, unsigned c, unsigned d) {
  uint4v v; v[0] = a; v[1] = b; v[2] = c; v[3] = d; return v;
}
static __device__ __forceinline__ short8 u4s8(uint4v w) {
  union { uint4v u; short8 s; } x; x.u = w; return x.s;
}

__global__ void tem_init_m(const float* __restrict__ Min, float* __restrict__ oM) {
  int i = blockIdx.x * 256 + threadIdx.x;
  if (i < PD * PD) oM[i] = LAMDA * Min[i];
}

// ---- fragment state in WAVE-PRIVATE LDS (Pb) - R8 structure (passed, 1.17M
// bank conflicts, barrier-free iteration loop). R9 change: d/s staging writes
// are ROW-MAJOR coalesced packed-u32 (R1's proven-clean path; feature-major
// 64B scatter was the 1.03 GB / ~1000 us HBM-write bottleneck, R5-R8).
#define LDMS(nt, kc) (*(const short8*)(Ms + (((nt) * 32 + cl) * MS_KS + (kc) * 16 + hi * 8)))
#define PFLD(KC) (((const uint4v*)Pb)[(pbW + (KC)) * 64 + lane])
#define PFST(KC, V) (((uint4v*)Pb)[(pbW + (KC)) * 64 + lane] = (V))

#define STEP(KC) do { \
  const short8 _b = u4s8(PFLD(KC)); \
  acc0 = __builtin_amdgcn_mfma_f32_32x32x16_bf16(LDMS(0, KC), _b, acc0, 0, 0, 0); \
  acc1 = __builtin_amdgcn_mfma_f32_32x32x16_bf16(LDMS(1, KC), _b, acc1, 0, 0, 0); \
  acc2 = __builtin_amdgcn_mfma_f32_32x32x16_bf16(LDMS(2, KC), _b, acc2, 0, 0, 0); \
  acc3 = __builtin_amdgcn_mfma_f32_32x32x16_bf16(LDMS(3, KC), _b, acc3, 0, 0, 0); \
  acc4 = __builtin_amdgcn_mfma_f32_32x32x16_bf16(LDMS(4, KC), _b, acc4, 0, 0, 0); \
  acc5 = __builtin_amdgcn_mfma_f32_32x32x16_bf16(LDMS(5, KC), _b, acc5, 0, 0, 0); \
  acc6 = __builtin_amdgcn_mfma_f32_32x32x16_bf16(LDMS(6, KC), _b, acc6, 0, 0, 0); \
  __builtin_amdgcn_sched_barrier(0); \
} while (0)

#define REPACK_LO(ACC, KC) do { \
  unsigned P0 = pkbf(fp_nl(ACC[0]), fp_nl(ACC[1])); \
  unsigned P1 = pkbf(fp_nl(ACC[2]), fp_nl(ACC[3])); \
  unsigned P2 = pkbf(fp_nl(ACC[4]), fp_nl(ACC[5])); \
  unsigned P3 = pkbf(fp_nl(ACC[6]), fp_nl(ACC[7])); \
  swap32(P0, P2); swap32(P1, P3); \
  PFST(KC, mk4(P0, P1, P2, P3)); \
} while (0)

#define REPACK_HI(ACC, KC) do { \
  unsigned P4 = pkbf(fp_nl(ACC[8]),  fp_nl(ACC[9])); \
  unsigned P5 = pkbf(fp_nl(ACC[10]), fp_nl(ACC[11])); \
  unsigned P6 = pkbf(fp_nl(ACC[12]), fp_nl(ACC[13])); \
  unsigned P7 = pkbf(fp_nl(ACC[14]), fp_nl(ACC[15])); \
  swap32(P4, P6); swap32(P5, P7); \
  PFST(KC, mk4(P4, P5, P6, P7)); \
} while (0)

// lane (hi,cl) holds features BB..BB+7 of LDS fragment KC, BB = kc*16 (+8 if hi)
#define FOR_LO(M_) M_(0,0) M_(1,16) M_(2,32) M_(3,48) M_(4,64) M_(5,80) \
                   M_(6,96) M_(7,112) M_(8,128) M_(9,144) M_(10,160) M_(11,176) M_(12,192)
#define FOR_HI(M_) M_(0,8) M_(1,24) M_(2,40) M_(3,56) M_(4,72) M_(5,88) \
                   M_(6,104) M_(7,120) M_(8,136) M_(9,152) M_(10,168) M_(11,184)

#define INX(KC, BB) PFST(KC, mk4( \
  pkbf(xcv[((BB) + 0) % 10], xcv[((BB) + 1) % 10]), \
  pkbf(xcv[((BB) + 2) % 10], xcv[((BB) + 3) % 10]), \
  pkbf(xcv[((BB) + 4) % 10], xcv[((BB) + 5) % 10]), \
  pkbf(xcv[((BB) + 6) % 10], xcv[((BB) + 7) % 10])));
#define ING(KC, BB) PFST(KC, mk4( \
  pkbf(g2v[((BB) + 0) / 10], g2v[((BB) + 1) / 10]), \
  pkbf(g2v[((BB) + 2) / 10], g2v[((BB) + 3) / 10]), \
  pkbf(g2v[((BB) + 4) / 10], g2v[((BB) + 5) / 10]), \
  pkbf(g2v[((BB) + 6) / 10], g2v[((BB) + 7) / 10])));

#define E1W(W, F) { bins[(F) / 10] += bf2f((unsigned short)((W) & 0xFFFFu)); \
                    bins[((F) + 1) / 10] += bf2f((unsigned short)((W) >> 16)); }
#define E1PF(KC, BB) { const uint4v W_ = PFLD(KC); \
  E1W(W_[0], (BB) + 0) E1W(W_[1], (BB) + 2) E1W(W_[2], (BB) + 4) E1W(W_[3], (BB) + 6) }

#define E2AW(W, F) { ta[(F) % 10] += bf2f((unsigned short)((W) & 0xFFFFu)); \
                     ta[((F) + 1) % 10] += bf2f((unsigned short)((W) >> 16)); }
#define E2APF(KC, BB) { const uint4v W_ = PFLD(KC); \
  E2AW(W_[0], (BB) + 0) E2AW(W_[1], (BB) + 2) E2AW(W_[2], (BB) + 4) E2AW(W_[3], (BB) + 6) }

// 256 threads (4 waves, 1/SIMD): the only config that never spilled (R1).
__global__ __launch_bounds__(256, 1) void tem_main(
    const float* __restrict__ xin, const float* __restrict__ gin,
    const float* __restrict__ Min, const float* __restrict__ Wc,
    const float* __restrict__ W1ie, const float* __restrict__ b1ie,
    const float* __restrict__ W2ie, const float* __restrict__ b2ie,
    const float* __restrict__ W1gg, const float* __restrict__ b1gg,
    const float* __restrict__ W2gg, const float* __restrict__ b2gg,
    const float* __restrict__ Wsp, const float* __restrict__ bsp,
    float* __restrict__ o_ginf, float* __restrict__ o_xinf,
    float* __restrict__ o_g, float* __restrict__ o_x,
    unsigned short* __restrict__ dWp, unsigned short* __restrict__ sWp) {
  // LDS: 96768 + 53248 + 2560 + 10240 = 162816 B
  __shared__ __attribute__((aligned(16))) unsigned short Ms[224 * MS_KS];
  __shared__ __attribute__((aligned(16))) unsigned Pb[4 * 13 * 64 * 4];
  __shared__ unsigned short xcS[128 * 10];
  __shared__ float g2S[128 * 20];

  const int tid = threadIdx.x;
  const int lane = tid & 63;
  const int wid = tid >> 6;      // 0..3
  const int cl = lane & 31;
  const int hi = lane >> 5;
  const int pbW = wid * 13;      // per-wave Pb fragment base

  // ---- stage M^T (+kappa*I) once per block
  {
    unsigned* Ms32 = (unsigned*)Ms;
    for (int i = tid; i < 224 * MS_KS / 2; i += 256) Ms32[i] = 0u;
  }
  __syncthreads();
  for (int i = tid; i < 200 * 224; i += 256) {
    const int k = i / 224, n = i - k * 224;
    if (n < 200) {
      float v = Min[k * 200 + n];
      if (k == n) v += KAPPA;
      Ms[n * MS_KS + k] = f2bf(v);
    }
  }

#pragma unroll 1
  for (int chunk = 0; chunk < 4; ++chunk) {
    const int r0 = (blockIdx.x * 4 + chunk) * 128;

    __syncthreads();   // Ms ready (chunk 0) / all waves done with Pb,xcS,g2S (chunks 1+)

    // prologue: threads 0..127 -> g2 MLP; 128..255 -> xc
    if (tid < 128) {
      const int rq = r0 + tid;
      float gv[20];
#pragma unroll
      for (int i = 0; i < 20; ++i) gv[i] = gin[(size_t)rq * 20 + i];
      float h[40];
#pragma unroll
      for (int u = 0; u < 40; ++u) h[u] = b1gg[u];
#pragma unroll
      for (int i = 0; i < 20; ++i)
#pragma unroll
        for (int u = 0; u < 40; ++u) h[u] += gv[i] * W1gg[i * 40 + u];
#pragma unroll
      for (int u = 0; u < 40; ++u) h[u] = (h[u] > 0.f) ? h[u] : (expf(h[u]) - 1.f);
#pragma unroll
      for (int o = 0; o < 20; ++o) {
        float v = b2gg[o];
#pragma unroll
        for (int u = 0; u < 40; ++u) v += h[u] * W2gg[u * 20 + o];
        g2S[tid * 20 + o] = tanhf(v);
      }
    } else {
      const int rr2 = tid - 128;
      const int rq = r0 + rr2;
      float xc[10];
#pragma unroll
      for (int o = 0; o < 10; ++o) xc[o] = 0.f;
      for (int j = 0; j < 45; ++j) {
        const float xv = xin[(size_t)rq * 45 + j];
#pragma unroll
        for (int o = 0; o < 10; ++o) xc[o] += xv * Wc[j * 10 + o];
      }
#pragma unroll
      for (int o = 0; o < 10; ++o) xcS[rr2 * 10 + o] = f2bf(xc[o]);
    }
    __syncthreads();

    // P1: write g_ and x_ outputs (coalesced)
    for (int i = tid; i < 128 * 200; i += 256) {
      const int rP = i / 200, j = i - rP * 200;
      o_g[(size_t)(r0 + rP) * 200 + j] = g2S[rP * 20 + j / 10];
      o_x[(size_t)(r0 + rP) * 200 + j] = bf2f(xcS[rP * 10 + (j % 10)]);
    }

    const int rr = wid * 32 + cl;   // block-row this lane owns (0..127)
    const int r = r0 + rr;          // global row

#pragma unroll 1
    for (int ret = 0; ret < 2; ++ret) {
      if (ret == 0) {
        float xcv[10];
#pragma unroll
        for (int o = 0; o < 10; ++o) xcv[o] = bf2f(xcS[rr * 10 + o]);
        if (hi == 0) { FOR_LO(INX) }
        else         { FOR_HI(INX) PFST(12, mk4(0u, 0u, 0u, 0u)); }
      } else {
        float g2v[20];
#pragma unroll
        for (int o = 0; o < 20; ++o) g2v[o] = g2S[rr * 20 + o];
        if (hi == 0) { FOR_LO(ING) }
        else         { FOR_HI(ING) PFST(12, mk4(0u, 0u, 0u, 0u)); }
      }

      // iteration loop: barrier-free (wave-private Pb; Ms read-only)
#pragma unroll 1
      for (int it = 0; it < 5; ++it) {
        f32x16 acc0 = {}, acc1 = {}, acc2 = {}, acc3 = {}, acc4 = {}, acc5 = {}, acc6 = {};
        STEP(0);  STEP(1);  STEP(2);  STEP(3);  STEP(4);  STEP(5);  STEP(6);
        STEP(7);  STEP(8);  STEP(9);  STEP(10); STEP(11); STEP(12);
        REPACK_LO(acc0, 0);  REPACK_HI(acc0, 1);
        REPACK_LO(acc1, 2);  REPACK_HI(acc1, 3);
        REPACK_LO(acc2, 4);  REPACK_HI(acc2, 5);
        REPACK_LO(acc3, 6);  REPACK_HI(acc3, 7);
        REPACK_LO(acc4, 8);  REPACK_HI(acc4, 9);
        REPACK_LO(acc5, 10); REPACK_HI(acc5, 11);
        REPACK_LO(acc6, 12);              // hi half of tile 6 (n=208..223) dropped
      }

      if (ret == 0) {
        // E1: g_inf = clip(MLP(px @ W_repeat^T)) - per-lane, own fragments
        float bins[20];
#pragma unroll
        for (int t = 0; t < 20; ++t) bins[t] = 0.f;
        if (hi == 0) { FOR_LO(E1PF) } else { FOR_HI(E1PF) }
#pragma unroll
        for (int t = 0; t < 20; ++t) bins[t] += __shfl_xor(bins[t], 32);
        float h[40];
#pragma unroll
        for (int u = 0; u < 40; ++u) h[u] = b1ie[u];
#pragma unroll
        for (int gg = 0; gg < 20; ++gg) {
          const float bv = bins[gg];
#pragma unroll
          for (int u = 0; u < 40; ++u) h[u] += bv * W1ie[gg * 40 + u];
        }
#pragma unroll
        for (int u = 0; u < 40; ++u) h[u] = (h[u] > 0.f) ? h[u] : (expf(h[u]) - 1.f);
#pragma unroll
        for (int oi = 0; oi < 10; ++oi) {
          const int o = hi * 10 + oi;
          float v = b2ie[o];
#pragma unroll
          for (int u = 0; u < 40; ++u) v += h[u] * W2ie[u * 20 + o];
          o_ginf[(size_t)r * 20 + o] = fminf(1.f, fmaxf(-1.f, v));
        }
      } else {
        // E2a: x_inf - per-lane, own fragments
        float ta[10];
#pragma unroll
        for (int t = 0; t < 10; ++t) ta[t] = 0.f;
        if (hi == 0) { FOR_LO(E2APF) } else { FOR_HI(E2APF) }
#pragma unroll
        for (int t = 0; t < 10; ++t) ta[t] += __shfl_xor(ta[t], 32);
        {
          const int o0 = hi ? 23 : 0, o1 = hi ? 45 : 23;
          for (int o = o0; o < o1; ++o) {
            float v = bsp[o];
#pragma unroll
            for (int a = 0; a < 10; ++a) v += ta[a] * Wsp[a * 45 + o];
            o_xinf[(size_t)r * 45 + o] = v;
          }
        }
        // E2b: d/s staging - ROW-MAJOR coalesced packed u32 (R1's clean path).
        // Flat loop reads p from Pb via inverse fragment mapping.
        __syncthreads();   // all waves' final REPACKs visible
        {
          unsigned int* dW32 = (unsigned int*)dWp;
          unsigned int* sW32 = (unsigned int*)sWp;
          for (int i = tid; i < 128 * 100; i += 256) {
            const int rD = i / 100, jp = i - rD * 100;
            const int j0 = jp * 2;
            const int wD = rD >> 5, clD = rD & 31;
            const int kcf = j0 >> 4, rem = j0 & 15;
            const int hif = rem >> 3, jw = (rem & 7) >> 1;
            const unsigned word = Pb[((wD * 13 + kcf) * 64 + hif * 32 + clD) * 4 + jw];
            const float p0 = bf2f((unsigned short)(word & 0xFFFFu));
            const float p1 = bf2f((unsigned short)(word >> 16));
            const float x0 = bf2f(xcS[rD * 10 + (j0 % 10)]);
            const float x1 = bf2f(xcS[rD * 10 + ((j0 + 1) % 10)]);
            const float pi0 = fp_nl(g2S[rD * 20 + (j0 / 10)] * x0);
            const float pi1 = fp_nl(g2S[rD * 20 + ((j0 + 1) / 10)] * x1);
            const unsigned dpack = (unsigned)f2bf(pi0 - p0) | ((unsigned)f2bf(pi1 - p1) << 16);
            const unsigned spack = (unsigned)f2bf(pi0 + p0) | ((unsigned)f2bf(pi1 + p1) << 16);
            const size_t idx = (size_t)(r0 + rD) * 100 + jp;
            dW32[idx] = dpack;
            sW32[idx] = spack;
          }
        }
      }
    }
  }
}

// R1's proven hebb: row-major d/s input, LDS transpose, split-K 128 blocks.
__global__ __launch_bounds__(448, 1) void tem_hebb(
    const unsigned short* __restrict__ dWp, const unsigned short* __restrict__ sWp,
    float* __restrict__ oM) {
  __shared__ __attribute__((aligned(16))) unsigned short dT[224 * HB_RS];
  __shared__ __attribute__((aligned(16))) unsigned short sT[224 * HB_RS];
  const int tid = threadIdx.x;
  const int lane = tid & 63, wid = tid >> 6;   // 7 waves
  const int cl = lane & 31, hi = lane >> 5;
  for (int i = tid; i < 224 * HB_RS; i += 448) { dT[i] = 0; sT[i] = 0; }
  f32x16 hacc[7];
#pragma unroll
  for (int nt = 0; nt < 7; ++nt)
#pragma unroll
    for (int q = 0; q < 16; ++q) hacc[nt][q] = 0.f;
  const int kbase = blockIdx.x * 1024;
  for (int sub = 0; sub < 16; ++sub) {
    __syncthreads();
    const int kb = kbase + sub * 64;
    for (int i = tid; i < 64 * 50; i += 448) {
      const int rr = i / 50, fq = i - rr * 50;
      const int f0 = fq * 4;
      const short4v d4 = *(const short4v*)(dWp + ((size_t)(kb + rr) * 200 + f0));
      const short4v s4 = *(const short4v*)(sWp + ((size_t)(kb + rr) * 200 + f0));
#pragma unroll
      for (int q = 0; q < 4; ++q) {
        dT[(f0 + q) * HB_RS + rr] = (unsigned short)d4[q];
        sT[(f0 + q) * HB_RS + rr] = (unsigned short)s4[q];
      }
    }
    __syncthreads();
#pragma unroll
    for (int kc = 0; kc < 4; ++kc) {
      const short8 af = *(const short8*)(dT + ((wid * 32 + cl) * HB_RS + kc * 16 + hi * 8));
#pragma unroll
      for (int nt = 0; nt < 7; ++nt) {
        const short8 bfr = *(const short8*)(sT + ((nt * 32 + cl) * HB_RS + kc * 16 + hi * 8));
        hacc[nt] = __builtin_amdgcn_mfma_f32_32x32x16_bf16(af, bfr, hacc[nt], 0, 0, 0);
      }
    }
  }
  const float scale = YITA / (float)B_TOTAL;
#pragma unroll
  for (int nt = 0; nt < 7; ++nt) {
    const int j = nt * 32 + cl;
    if (j < 200) {
#pragma unroll
      for (int rg = 0; rg < 16; ++rg) {
        const int ii = wid * 32 + (rg & 3) + 8 * (rg >> 2) + 4 * hi;
        if (ii < 200) atomicAdd(&oM[ii * 200 + j], hacc[nt][rg] * scale);
      }
    }
  }
}

extern "C" void kernel_launch(void* const* d_in, const int* in_sizes, int n_in,
                              void* d_out, int out_size, void* d_ws, size_t ws_size,
                              hipStream_t stream) {
  (void)in_sizes; (void)n_in; (void)out_size; (void)ws_size;
  const float* xin  = (const float*)d_in[0];
  const float* gin  = (const float*)d_in[1];
  const float* Min  = (const float*)d_in[2];
  const float* Wc   = (const float*)d_in[3];
  const float* W1ie = (const float*)d_in[4];
  const float* b1ie = (const float*)d_in[5];
  const float* W2ie = (const float*)d_in[6];
  const float* b2ie = (const float*)d_in[7];
  const float* W1gg = (const float*)d_in[8];
  const float* b1gg = (const float*)d_in[9];
  const float* W2gg = (const float*)d_in[10];
  const float* b2gg = (const float*)d_in[11];
  const float* Wsp  = (const float*)d_in[12];
  const float* bsp  = (const float*)d_in[13];

  float* out = (float*)d_out;
  float* o_ginf = out;
  float* o_xinf = out + (size_t)B_TOTAL * 20;
  float* o_g    = out + (size_t)B_TOTAL * 65;
  float* o_x    = out + (size_t)B_TOTAL * 265;
  float* o_M    = out + (size_t)B_TOTAL * 465;

  unsigned short* dWp = (unsigned short*)d_ws;
  unsigned short* sWp = dWp + (size_t)B_TOTAL * PD;

  tem_init_m<<<(PD * PD + 255) / 256, 256, 0, stream>>>(Min, o_M);
  tem_main<<<256, 256, 0, stream>>>(xin, gin, Min, Wc, W1ie, b1ie, W2ie, b2ie,
                                    W1gg, b1gg, W2gg, b2gg, Wsp, bsp,
                                    o_ginf, o_xinf, o_g, o_x, dWp, sWp);
  tem_hebb<<<128, 448, 0, stream>>>(dWp, sWp, o_M);
}

// Round 10
// 572.959 us; speedup vs baseline: 2.2254x; 1.0216x over previous
//
#include <hip/hip_runtime.h>

#define B_TOTAL 131072
#define PD 200
#define KAPPA 0.8f
#define LAMDA 0.9999f
#define YITA 0.5f
#define MS_KS 216   // M LDS k-stride (27 16B slots, odd -> minimal-conflict A reads)
#define HB_RS 72    // hebb LDS row-stride (9 slots, odd)

typedef short short8 __attribute__((ext_vector_type(8)));
typedef short short4v __attribute__((ext_vector_type(4)));
typedef float f32x16 __attribute__((ext_vector_type(16)));
typedef unsigned uint4v __attribute__((ext_vector_type(4)));

static __device__ __forceinline__ float bf2f(unsigned short h) {
  union { unsigned u; float f; } v; v.u = ((unsigned)h) << 16; return v.f;
}
static __device__ __forceinline__ unsigned short f2bf(float f) {
  union { float f; unsigned u; } v; v.f = f;
  unsigned r = v.u + 0x7FFFu + ((v.u >> 16) & 1u);
  return (unsigned short)(r >> 16);
}
static __device__ __forceinline__ float fp_nl(float v) {  // clip(leaky_relu(v),-1,1)
  float t = fmaxf(v, 0.01f * v);
  return fminf(1.f, fmaxf(-1.f, t));
}
static __device__ __forceinline__ unsigned pkbf(float lo, float hi) {
  unsigned r;
  asm("v_cvt_pk_bf16_f32 %0, %1, %2" : "=v"(r) : "v"(lo), "v"(hi));
  return r;
}
// verified R2-R9: swaps 32-lane halves between a,b
static __device__ __forceinline__ void swap32(unsigned &a, unsigned &b) {
  asm("s_nop 1\n\tv_permlane32_swap_b32 %0, %1" : "+v"(a), "+v"(b));
}
static __device__ __forceinline__ uint4v mk4(unsigned a, unsigned b, unsigned c, unsigned d) {
  uint4v v; v[0] = a; v[1] = b; v[2] = c; v[3] = d; return v;
}
static __device__ __forceinline__ short8 u4s8(uint4v w) {
  union { uint4v u; short8 s; } x; x.u = w; return x.s;
}

__global__ void tem_init_m(const float* __restrict__ Min, float* __restrict__ oM) {
  int i = blockIdx.x * 256 + threadIdx.x;
  if (i < PD * PD) oM[i] = LAMDA * Min[i];
}

// ---- R10: DUAL-RETRIEVAL interleave. Both rets share each Ms A-fragment
// load: ret0 (x-cue) B-frags in 13 named VGPR quads + VGPR accs (builtin);
// ret1 (g-cue) B-frags in wave-private LDS (Pb, E2b reads them there) + AGPR
// accs via R7-proven "+a" asm MFMA. 8 ds_reads -> 14 MFMAs per lgkm wait
// (was 8 -> 7, twice over). Staging stays R9's row-major coalesced path.
#define LDMS(nt, kc) (*(const short8*)(Ms + (((nt) * 32 + cl) * MS_KS + (kc) * 16 + hi * 8)))
#define PFLD(KC) (((const uint4v*)Pb)[(pbW + (KC)) * 64 + lane])
#define PFST(KC, V) (((uint4v*)Pb)[(pbW + (KC)) * 64 + lane] = (V))

#define MFMA_V(ACC, A, B) ACC = __builtin_amdgcn_mfma_f32_32x32x16_bf16(A, B, ACC, 0, 0, 0)
#define MFMA_AG(ACC, A, B) asm("v_mfma_f32_32x32x16_bf16 %0, %1, %2, %0" : "+a"(ACC) : "v"(A), "v"(B))

#define STEP2(PFA, KC) do { \
  const short8 _bA = u4s8(PFA); \
  const short8 _bB = u4s8(PFLD(KC)); \
  { const short8 _a = LDMS(0, KC); MFMA_V(accA0, _a, _bA); MFMA_AG(accB0, _a, _bB); } \
  { const short8 _a = LDMS(1, KC); MFMA_V(accA1, _a, _bA); MFMA_AG(accB1, _a, _bB); } \
  { const short8 _a = LDMS(2, KC); MFMA_V(accA2, _a, _bA); MFMA_AG(accB2, _a, _bB); } \
  { const short8 _a = LDMS(3, KC); MFMA_V(accA3, _a, _bA); MFMA_AG(accB3, _a, _bB); } \
  { const short8 _a = LDMS(4, KC); MFMA_V(accA4, _a, _bA); MFMA_AG(accB4, _a, _bB); } \
  { const short8 _a = LDMS(5, KC); MFMA_V(accA5, _a, _bA); MFMA_AG(accB5, _a, _bB); } \
  { const short8 _a = LDMS(6, KC); MFMA_V(accA6, _a, _bA); MFMA_AG(accB6, _a, _bB); } \
  __builtin_amdgcn_sched_barrier(0); \
} while (0)

// register-target repack (ret0)
#define REPACK_LO_R(ACC, PF) do { \
  unsigned P0 = pkbf(fp_nl(ACC[0]), fp_nl(ACC[1])); \
  unsigned P1 = pkbf(fp_nl(ACC[2]), fp_nl(ACC[3])); \
  unsigned P2 = pkbf(fp_nl(ACC[4]), fp_nl(ACC[5])); \
  unsigned P3 = pkbf(fp_nl(ACC[6]), fp_nl(ACC[7])); \
  swap32(P0, P2); swap32(P1, P3); \
  PF = mk4(P0, P1, P2, P3); \
} while (0)
#define REPACK_HI_R(ACC, PF) do { \
  unsigned P4 = pkbf(fp_nl(ACC[8]),  fp_nl(ACC[9])); \
  unsigned P5 = pkbf(fp_nl(ACC[10]), fp_nl(ACC[11])); \
  unsigned P6 = pkbf(fp_nl(ACC[12]), fp_nl(ACC[13])); \
  unsigned P7 = pkbf(fp_nl(ACC[14]), fp_nl(ACC[15])); \
  swap32(P4, P6); swap32(P5, P7); \
  PF = mk4(P4, P5, P6, P7); \
} while (0)
// LDS-target repack (ret1)
#define REPACK_LO_L(ACC, KC) do { \
  unsigned P0 = pkbf(fp_nl(ACC[0]), fp_nl(ACC[1])); \
  unsigned P1 = pkbf(fp_nl(ACC[2]), fp_nl(ACC[3])); \
  unsigned P2 = pkbf(fp_nl(ACC[4]), fp_nl(ACC[5])); \
  unsigned P3 = pkbf(fp_nl(ACC[6]), fp_nl(ACC[7])); \
  swap32(P0, P2); swap32(P1, P3); \
  PFST(KC, mk4(P0, P1, P2, P3)); \
} while (0)
#define REPACK_HI_L(ACC, KC) do { \
  unsigned P4 = pkbf(fp_nl(ACC[8]),  fp_nl(ACC[9])); \
  unsigned P5 = pkbf(fp_nl(ACC[10]), fp_nl(ACC[11])); \
  unsigned P6 = pkbf(fp_nl(ACC[12]), fp_nl(ACC[13])); \
  unsigned P7 = pkbf(fp_nl(ACC[14]), fp_nl(ACC[15])); \
  swap32(P4, P6); swap32(P5, P7); \
  PFST(KC, mk4(P4, P5, P6, P7)); \
} while (0)

// lane (hi,cl) holds features BB..BB+7; register set (ret0) / LDS set (ret1)
#define FORR_LO(M_) M_(pfA0,0) M_(pfA1,16) M_(pfA2,32) M_(pfA3,48) M_(pfA4,64) M_(pfA5,80) \
                    M_(pfA6,96) M_(pfA7,112) M_(pfA8,128) M_(pfA9,144) M_(pfA10,160) M_(pfA11,176) M_(pfA12,192)
#define FORR_HI(M_) M_(pfA0,8) M_(pfA1,24) M_(pfA2,40) M_(pfA3,56) M_(pfA4,72) M_(pfA5,88) \
                    M_(pfA6,104) M_(pfA7,120) M_(pfA8,136) M_(pfA9,152) M_(pfA10,168) M_(pfA11,184)
#define FORL_LO(M_) M_(0,0) M_(1,16) M_(2,32) M_(3,48) M_(4,64) M_(5,80) \
                    M_(6,96) M_(7,112) M_(8,128) M_(9,144) M_(10,160) M_(11,176) M_(12,192)
#define FORL_HI(M_) M_(0,8) M_(1,24) M_(2,40) M_(3,56) M_(4,72) M_(5,88) \
                    M_(6,104) M_(7,120) M_(8,136) M_(9,152) M_(10,168) M_(11,184)

#define INX(PF, BB) PF = mk4( \
  pkbf(xcv[((BB) + 0) % 10], xcv[((BB) + 1) % 10]), \
  pkbf(xcv[((BB) + 2) % 10], xcv[((BB) + 3) % 10]), \
  pkbf(xcv[((BB) + 4) % 10], xcv[((BB) + 5) % 10]), \
  pkbf(xcv[((BB) + 6) % 10], xcv[((BB) + 7) % 10]));
#define ING(KC, BB) PFST(KC, mk4( \
  pkbf(g2v[((BB) + 0) / 10], g2v[((BB) + 1) / 10]), \
  pkbf(g2v[((BB) + 2) / 10], g2v[((BB) + 3) / 10]), \
  pkbf(g2v[((BB) + 4) / 10], g2v[((BB) + 5) / 10]), \
  pkbf(g2v[((BB) + 6) / 10], g2v[((BB) + 7) / 10])));

#define E1W(W, F) { bins[(F) / 10] += bf2f((unsigned short)((W) & 0xFFFFu)); \
                    bins[((F) + 1) / 10] += bf2f((unsigned short)((W) >> 16)); }
#define E1PF(PF, BB) { E1W(PF[0], (BB) + 0) E1W(PF[1], (BB) + 2) E1W(PF[2], (BB) + 4) E1W(PF[3], (BB) + 6) }

#define E2AW(W, F) { ta[(F) % 10] += bf2f((unsigned short)((W) & 0xFFFFu)); \
                     ta[((F) + 1) % 10] += bf2f((unsigned short)((W) >> 16)); }
#define E2APF(KC, BB) { const uint4v W_ = PFLD(KC); \
  E2AW(W_[0], (BB) + 0) E2AW(W_[1], (BB) + 2) E2AW(W_[2], (BB) + 4) E2AW(W_[3], (BB) + 6) }

// 256 threads (4 waves, 1/SIMD): the only spill-free config (R1/R6/R9).
__global__ __launch_bounds__(256, 1) void tem_main(
    const float* __restrict__ xin, const float* __restrict__ gin,
    const float* __restrict__ Min, const float* __restrict__ Wc,
    const float* __restrict__ W1ie, const float* __restrict__ b1ie,
    const float* __restrict__ W2ie, const float* __restrict__ b2ie,
    const float* __restrict__ W1gg, const float* __restrict__ b1gg,
    const float* __restrict__ W2gg, const float* __restrict__ b2gg,
    const float* __restrict__ Wsp, const float* __restrict__ bsp,
    float* __restrict__ o_ginf, float* __restrict__ o_xinf,
    float* __restrict__ o_g, float* __restrict__ o_x,
    unsigned short* __restrict__ dWp, unsigned short* __restrict__ sWp) {
  // LDS: 96768 + 53248 + 2560 + 10240 = 162816 B
  __shared__ __attribute__((aligned(16))) unsigned short Ms[224 * MS_KS];
  __shared__ __attribute__((aligned(16))) unsigned Pb[4 * 13 * 64 * 4];
  __shared__ unsigned short xcS[128 * 10];
  __shared__ float g2S[128 * 20];

  const int tid = threadIdx.x;
  const int lane = tid & 63;
  const int wid = tid >> 6;      // 0..3
  const int cl = lane & 31;
  const int hi = lane >> 5;
  const int pbW = wid * 13;      // per-wave Pb fragment base

  // ---- stage M^T (+kappa*I) once per block
  {
    unsigned* Ms32 = (unsigned*)Ms;
    for (int i = tid; i < 224 * MS_KS / 2; i += 256) Ms32[i] = 0u;
  }
  __syncthreads();
  for (int i = tid; i < 200 * 224; i += 256) {
    const int k = i / 224, n = i - k * 224;
    if (n < 200) {
      float v = Min[k * 200 + n];
      if (k == n) v += KAPPA;
      Ms[n * MS_KS + k] = f2bf(v);
    }
  }

#pragma unroll 1
  for (int chunk = 0; chunk < 4; ++chunk) {
    const int r0 = (blockIdx.x * 4 + chunk) * 128;

    __syncthreads();   // Ms ready (chunk 0) / all waves done with Pb,xcS,g2S (chunks 1+)

    // prologue: threads 0..127 -> g2 MLP; 128..255 -> xc
    if (tid < 128) {
      const int rq = r0 + tid;
      float gv[20];
#pragma unroll
      for (int i = 0; i < 20; ++i) gv[i] = gin[(size_t)rq * 20 + i];
      float h[40];
#pragma unroll
      for (int u = 0; u < 40; ++u) h[u] = b1gg[u];
#pragma unroll
      for (int i = 0; i < 20; ++i)
#pragma unroll
        for (int u = 0; u < 40; ++u) h[u] += gv[i] * W1gg[i * 40 + u];
#pragma unroll
      for (int u = 0; u < 40; ++u) h[u] = (h[u] > 0.f) ? h[u] : (expf(h[u]) - 1.f);
#pragma unroll
      for (int o = 0; o < 20; ++o) {
        float v = b2gg[o];
#pragma unroll
        for (int u = 0; u < 40; ++u) v += h[u] * W2gg[u * 20 + o];
        g2S[tid * 20 + o] = tanhf(v);
      }
    } else {
      const int rr2 = tid - 128;
      const int rq = r0 + rr2;
      float xc[10];
#pragma unroll
      for (int o = 0; o < 10; ++o) xc[o] = 0.f;
      for (int j = 0; j < 45; ++j) {
        const float xv = xin[(size_t)rq * 45 + j];
#pragma unroll
        for (int o = 0; o < 10; ++o) xc[o] += xv * Wc[j * 10 + o];
      }
#pragma unroll
      for (int o = 0; o < 10; ++o) xcS[rr2 * 10 + o] = f2bf(xc[o]);
    }
    __syncthreads();

    // P1: write g_ and x_ outputs (coalesced)
    for (int i = tid; i < 128 * 200; i += 256) {
      const int rP = i / 200, j = i - rP * 200;
      o_g[(size_t)(r0 + rP) * 200 + j] = g2S[rP * 20 + j / 10];
      o_x[(size_t)(r0 + rP) * 200 + j] = bf2f(xcS[rP * 10 + (j % 10)]);
    }

    const int rr = wid * 32 + cl;   // block-row this lane owns (0..127)
    const int r = r0 + rr;          // global row

    // ---- init both retrievals
    uint4v pfA0, pfA1, pfA2, pfA3, pfA4, pfA5, pfA6, pfA7, pfA8, pfA9, pfA10, pfA11, pfA12;
    {
      float xcv[10];
#pragma unroll
      for (int o = 0; o < 10; ++o) xcv[o] = bf2f(xcS[rr * 10 + o]);
      if (hi == 0) { FORR_LO(INX) }
      else         { FORR_HI(INX) pfA12 = mk4(0u, 0u, 0u, 0u); }
    }
    {
      float g2v[20];
#pragma unroll
      for (int o = 0; o < 20; ++o) g2v[o] = g2S[rr * 20 + o];
      if (hi == 0) { FORL_LO(ING) }
      else         { FORL_HI(ING) PFST(12, mk4(0u, 0u, 0u, 0u)); }
    }

    // ---- 5 dual attractor iterations (barrier-free: wave-private Pb, RO Ms)
#pragma unroll 1
    for (int it = 0; it < 5; ++it) {
      f32x16 accA0 = {}, accA1 = {}, accA2 = {}, accA3 = {}, accA4 = {}, accA5 = {}, accA6 = {};
      f32x16 accB0 = {}, accB1 = {}, accB2 = {}, accB3 = {}, accB4 = {}, accB5 = {}, accB6 = {};
      STEP2(pfA0, 0);  STEP2(pfA1, 1);  STEP2(pfA2, 2);  STEP2(pfA3, 3);
      STEP2(pfA4, 4);  STEP2(pfA5, 5);  STEP2(pfA6, 6);  STEP2(pfA7, 7);
      STEP2(pfA8, 8);  STEP2(pfA9, 9);  STEP2(pfA10, 10); STEP2(pfA11, 11);
      STEP2(pfA12, 12);
      REPACK_LO_R(accA0, pfA0);  REPACK_HI_R(accA0, pfA1);
      REPACK_LO_R(accA1, pfA2);  REPACK_HI_R(accA1, pfA3);
      REPACK_LO_R(accA2, pfA4);  REPACK_HI_R(accA2, pfA5);
      REPACK_LO_R(accA3, pfA6);  REPACK_HI_R(accA3, pfA7);
      REPACK_LO_R(accA4, pfA8);  REPACK_HI_R(accA4, pfA9);
      REPACK_LO_R(accA5, pfA10); REPACK_HI_R(accA5, pfA11);
      REPACK_LO_R(accA6, pfA12);
      REPACK_LO_L(accB0, 0);  REPACK_HI_L(accB0, 1);
      REPACK_LO_L(accB1, 2);  REPACK_HI_L(accB1, 3);
      REPACK_LO_L(accB2, 4);  REPACK_HI_L(accB2, 5);
      REPACK_LO_L(accB3, 6);  REPACK_HI_L(accB3, 7);
      REPACK_LO_L(accB4, 8);  REPACK_HI_L(accB4, 9);
      REPACK_LO_L(accB5, 10); REPACK_HI_L(accB5, 11);
      REPACK_LO_L(accB6, 12);             // hi half of tile 6 (n=208..223) dropped
    }

    // ---- E1: g_inf from ret0 (register fragments)
    {
      float bins[20];
#pragma unroll
      for (int t = 0; t < 20; ++t) bins[t] = 0.f;
      if (hi == 0) { FORR_LO(E1PF) } else { FORR_HI(E1PF) }
#pragma unroll
      for (int t = 0; t < 20; ++t) bins[t] += __shfl_xor(bins[t], 32);
      float h[40];
#pragma unroll
      for (int u = 0; u < 40; ++u) h[u] = b1ie[u];
#pragma unroll
      for (int gg = 0; gg < 20; ++gg) {
        const float bv = bins[gg];
#pragma unroll
        for (int u = 0; u < 40; ++u) h[u] += bv * W1ie[gg * 40 + u];
      }
#pragma unroll
      for (int u = 0; u < 40; ++u) h[u] = (h[u] > 0.f) ? h[u] : (expf(h[u]) - 1.f);
#pragma unroll
      for (int oi = 0; oi < 10; ++oi) {
        const int o = hi * 10 + oi;
        float v = b2ie[o];
#pragma unroll
        for (int u = 0; u < 40; ++u) v += h[u] * W2ie[u * 20 + o];
        o_ginf[(size_t)r * 20 + o] = fminf(1.f, fmaxf(-1.f, v));
      }
    }
    // ---- E2a: x_inf from ret1 (Pb fragments)
    {
      float ta[10];
#pragma unroll
      for (int t = 0; t < 10; ++t) ta[t] = 0.f;
      if (hi == 0) { FORL_LO(E2APF) } else { FORL_HI(E2APF) }
#pragma unroll
      for (int t = 0; t < 10; ++t) ta[t] += __shfl_xor(ta[t], 32);
      const int o0 = hi ? 23 : 0, o1 = hi ? 45 : 23;
      for (int o = o0; o < o1; ++o) {
        float v = bsp[o];
#pragma unroll
        for (int a = 0; a < 10; ++a) v += ta[a] * Wsp[a * 45 + o];
        o_xinf[(size_t)r * 45 + o] = v;
      }
    }
    // ---- E2b: d/s staging - row-major coalesced packed u32 (R9 path)
    __syncthreads();   // all waves' final ret1 REPACKs visible
    {
      unsigned int* dW32 = (unsigned int*)dWp;
      unsigned int* sW32 = (unsigned int*)sWp;
      for (int i = tid; i < 128 * 100; i += 256) {
        const int rD = i / 100, jp = i - rD * 100;
        const int j0 = jp * 2;
        const int wD = rD >> 5, clD = rD & 31;
        const int kcf = j0 >> 4, rem = j0 & 15;
        const int hif = rem >> 3, jw = (rem & 7) >> 1;
        const unsigned word = Pb[((wD * 13 + kcf) * 64 + hif * 32 + clD) * 4 + jw];
        const float p0 = bf2f((unsigned short)(word & 0xFFFFu));
        const float p1 = bf2f((unsigned short)(word >> 16));
        const float x0 = bf2f(xcS[rD * 10 + (j0 % 10)]);
        const float x1 = bf2f(xcS[rD * 10 + ((j0 + 1) % 10)]);
        const float pi0 = fp_nl(g2S[rD * 20 + (j0 / 10)] * x0);
        const float pi1 = fp_nl(g2S[rD * 20 + ((j0 + 1) / 10)] * x1);
        const unsigned dpack = (unsigned)f2bf(pi0 - p0) | ((unsigned)f2bf(pi1 - p1) << 16);
        const unsigned spack = (unsigned)f2bf(pi0 + p0) | ((unsigned)f2bf(pi1 + p1) << 16);
        const size_t idx = (size_t)(r0 + rD) * 100 + jp;
        dW32[idx] = dpack;
        sW32[idx] = spack;
      }
    }
  }
}

// R9's proven hebb: row-major d/s input, LDS transpose, split-K 128 blocks.
__global__ __launch_bounds__(448, 1) void tem_hebb(
    const unsigned short* __restrict__ dWp, const unsigned short* __restrict__ sWp,
    float* __restrict__ oM) {
  __shared__ __attribute__((aligned(16))) unsigned short dT[224 * HB_RS];
  __shared__ __attribute__((aligned(16))) unsigned short sT[224 * HB_RS];
  const int tid = threadIdx.x;
  const int lane = tid & 63, wid = tid >> 6;   // 7 waves
  const int cl = lane & 31, hi = lane >> 5;
  for (int i = tid; i < 224 * HB_RS; i += 448) { dT[i] = 0; sT[i] = 0; }
  f32x16 hacc[7];
#pragma unroll
  for (int nt = 0; nt < 7; ++nt)
#pragma unroll
    for (int q = 0; q < 16; ++q) hacc[nt][q] = 0.f;
  const int kbase = blockIdx.x * 1024;
  for (int sub = 0; sub < 16; ++sub) {
    __syncthreads();
    const int kb = kbase + sub * 64;
    for (int i = tid; i < 64 * 50; i += 448) {
      const int rr = i / 50, fq = i - rr * 50;
      const int f0 = fq * 4;
      const short4v d4 = *(const short4v*)(dWp + ((size_t)(kb + rr) * 200 + f0));
      const short4v s4 = *(const short4v*)(sWp + ((size_t)(kb + rr) * 200 + f0));
#pragma unroll
      for (int q = 0; q < 4; ++q) {
        dT[(f0 + q) * HB_RS + rr] = (unsigned short)d4[q];
        sT[(f0 + q) * HB_RS + rr] = (unsigned short)s4[q];
      }
    }
    __syncthreads();
#pragma unroll
    for (int kc = 0; kc < 4; ++kc) {
      const short8 af = *(const short8*)(dT + ((wid * 32 + cl) * HB_RS + kc * 16 + hi * 8));
#pragma unroll
      for (int nt = 0; nt < 7; ++nt) {
        const short8 bfr = *(const short8*)(sT + ((nt * 32 + cl) * HB_RS + kc * 16 + hi * 8));
        hacc[nt] = __builtin_amdgcn_mfma_f32_32x32x16_bf16(af, bfr, hacc[nt], 0, 0, 0);
      }
    }
  }
  const float scale = YITA / (float)B_TOTAL;
#pragma unroll
  for (int nt = 0; nt < 7; ++nt) {
    const int j = nt * 32 + cl;
    if (j < 200) {
#pragma unroll
      for (int rg = 0; rg < 16; ++rg) {
        const int ii = wid * 32 + (rg & 3) + 8 * (rg >> 2) + 4 * hi;
        if (ii < 200) atomicAdd(&oM[ii * 200 + j], hacc[nt][rg] * scale);
      }
    }
  }
}

extern "C" void kernel_launch(void* const* d_in, const int* in_sizes, int n_in,
                              void* d_out, int out_size, void* d_ws, size_t ws_size,
                              hipStream_t stream) {
  (void)in_sizes; (void)n_in; (void)out_size; (void)ws_size;
  const float* xin  = (const float*)d_in[0];
  const float* gin  = (const float*)d_in[1];
  const float* Min  = (const float*)d_in[2];
  const float* Wc   = (const float*)d_in[3];
  const float* W1ie = (const float*)d_in[4];
  const float* b1ie = (const float*)d_in[5];
  const float* W2ie = (const float*)d_in[6];
  const float* b2ie = (const float*)d_in[7];
  const float* W1gg = (const float*)d_in[8];
  const float* b1gg = (const float*)d_in[9];
  const float* W2gg = (const float*)d_in[10];
  const float* b2gg = (const float*)d_in[11];
  const float* Wsp  = (const float*)d_in[12];
  const float* bsp  = (const float*)d_in[13];

  float* out = (float*)d_out;
  float* o_ginf = out;
  float* o_xinf = out + (size_t)B_TOTAL * 20;
  float* o_g    = out + (size_t)B_TOTAL * 65;
  float* o_x    = out + (size_t)B_TOTAL * 265;
  float* o_M    = out + (size_t)B_TOTAL * 465;

  unsigned short* dWp = (unsigned short*)d_ws;
  unsigned short* sWp = dWp + (size_t)B_TOTAL * PD;

  tem_init_m<<<(PD * PD + 255) / 256, 256, 0, stream>>>(Min, o_M);
  tem_main<<<256, 256, 0, stream>>>(xin, gin, Min, Wc, W1ie, b1ie, W2ie, b2ie,
                                    W1gg, b1gg, W2gg, b2gg, Wsp, bsp,
                                    o_ginf, o_xinf, o_g, o_x, dWp, sWp);
  tem_hebb<<<128, 448, 0, stream>>>(dWp, sWp, o_M);
}